// Round 11
// baseline (269.888 us; speedup 1.0000x reference)
//
#include <hip/hip_runtime.h>
#include <math.h>

#define CAP 48       // max bucketed in-degree; Poisson(16), P(deg>=48) ~ 8e-11/node
#define PARTBITS 8   // 256 dsts per bin
#define BINW 256
#define NB 240       // routing blocks (phase A)
#define SEGCAP 48    // per-(bin,block) queue segment; mean 17, 7.5 sigma

typedef float f32x4 __attribute__((ext_vector_type(4)));
typedef __bf16 bf16x8 __attribute__((ext_vector_type(8)));
typedef unsigned short ushort8 __attribute__((ext_vector_type(8)));
typedef int i32x4 __attribute__((ext_vector_type(4)));
typedef int i32x2 __attribute__((ext_vector_type(2)));

__device__ __forceinline__ float leaky(float x){ return x > 0.f ? x : 0.2f * x; }
__device__ __forceinline__ float eluf(float x){ return x > 0.f ? x : __expf(x) - 1.f; }
__device__ __forceinline__ unsigned short f2bf(float f){  // RNE float->bf16
  unsigned u = __float_as_uint(f);
  u += 0x7FFF + ((u >> 16) & 1);
  return (unsigned short)(u >> 16);
}

// K1: compute vw in LDS, emit packed 64B node record:
// rec[n] = {x0..x5, as0..as3, ad0..ad3, pad, pad}  (4 x float4)
// Also (first 64 blocks) pre-pack W2 into bf16 MFMA B-fragment lane order.
__global__ __launch_bounds__(256) void k1_att1(const float* __restrict__ x,
    const float* __restrict__ W1, const float* __restrict__ as1,
    const float* __restrict__ ad1, const float* __restrict__ W2,
    unsigned short* __restrict__ Bfrag, float4* __restrict__ rec, int N){
  __shared__ float vw[48];
  int t = threadIdx.x;
  int gid = blockIdx.x * 256 + t;
  if (gid < 16384){
    int j  = gid & 7;
    int L  = (gid >> 3) & 63;
    int ct = (gid >> 9) & 3;
    int ks = gid >> 11;
    int k = ks*32 + ((L >> 4) & 3)*8 + j;
    int c = ct*16 + (L & 15);
    Bfrag[gid] = f2bf(W2[k*64 + c]);
  }
  if (t < 48){
    int side = t / 24, r = t % 24, f = r / 4, h = r % 4;
    const float* att = side ? ad1 : as1;
    float s = 0.f;
    for (int c = 0; c < 64; ++c) s += W1[f*256 + h*64 + c] * att[h*64 + c];
    vw[side*24 + f*4 + h] = s;
  }
  __syncthreads();
  int n = gid;
  if (n >= N) return;
  float xf[6];
  for (int f = 0; f < 6; ++f) xf[f] = x[n*6 + f];
  float as[4], ad[4];
  for (int h = 0; h < 4; ++h){
    float s = 0.f, d = 0.f;
    for (int f = 0; f < 6; ++f){ s += xf[f] * vw[f*4 + h]; d += xf[f] * vw[24 + f*4 + h]; }
    as[h] = s; ad[h] = d;
  }
  rec[n*4 + 0] = make_float4(xf[0], xf[1], xf[2], xf[3]);
  rec[n*4 + 1] = make_float4(xf[4], xf[5], as[0], as[1]);
  rec[n*4 + 2] = make_float4(as[2], as[3], ad[0], ad[1]);
  rec[n*4 + 3] = make_float4(ad[2], ad[3], 0.f, 0.f);
}

// K2a: route edges into per-(bin,block) queue segments; ranks from block-local
// LDS counters — zero global atomics. EXACT R9 version (replay-check proven).
__global__ __launch_bounds__(256) void k2a_route(const int* __restrict__ ei,
    int E, int NR, i32x2* __restrict__ queue, int* __restrict__ qcnt){
  __shared__ int lcnt[512];
  int t = threadIdx.x, blk = blockIdx.x;
  for (int i = t; i < NR; i += 256) lcnt[i] = 0;
  __syncthreads();
  int E4 = E >> 2;
  const i32x4* s4 = (const i32x4*)ei;
  const i32x4* d4 = (const i32x4*)(ei + E);
  for (int i = blk*256 + t; i < E4; i += NB*256){
    i32x4 s = __builtin_nontemporal_load(s4 + i);
    i32x4 d = __builtin_nontemporal_load(d4 + i);
    #pragma unroll
    for (int j = 0; j < 4; ++j){
      int p = d[j] >> PARTBITS;
      int r = atomicAdd(&lcnt[p], 1);
      if (r < SEGCAP){ i32x2 v = {d[j], s[j]}; queue[((size_t)p*NB + blk)*SEGCAP + r] = v; }
    }
  }
  if (blk == 0 && t < (E & 3)){
    int e = E4*4 + t;
    int dd = ei[E + e], ss = ei[e];
    int p = dd >> PARTBITS;
    int r = atomicAdd(&lcnt[p], 1);
    if (r < SEGCAP){ i32x2 v = {dd, ss}; queue[((size_t)p*NB + blk)*SEGCAP + r] = v; }
  }
  __syncthreads();
  for (int i = t; i < NR; i += 256) qcnt[(size_t)i*NB + blk] = lcnt[i];
}

// K2b: one block per bin (256 dsts). Coalesced segment reads -> LDS scatter
// (49KB slab, LDS atomics) -> dense int4 write-out. EXACT R9 version.
__global__ __launch_bounds__(1024) void k2b_build(const i32x2* __restrict__ queue,
    const int* __restrict__ qcnt, int* __restrict__ cnt, int* __restrict__ bucket){
  __shared__ int lc[BINW];
  __shared__ int lq[NB];
  __shared__ int lbuck[BINW*CAP];   // 49KB
  int t = threadIdx.x, bin = blockIdx.x;
  if (t < BINW) lc[t] = 0;
  for (int i = t; i < NB; i += 1024) lq[i] = min(qcnt[(size_t)bin*NB + i], SEGCAP);
  __syncthreads();
  const i32x2* q = queue + (size_t)bin*NB*SEGCAP;
  const int T = NB * SEGCAP;
  for (int idx = t; idx < T; idx += 1024){
    int b = idx / SEGCAP;
    int i = idx - b*SEGCAP;
    if (i < lq[b]){
      i32x2 pr = q[idx];
      int ld = pr.x & (BINW-1);
      int pos = atomicAdd(&lc[ld], 1);
      if (pos < CAP) lbuck[ld*CAP + pos] = pr.y;
    }
  }
  __syncthreads();
  const int4* bsrc = (const int4*)lbuck;
  int4* bdst = (int4*)(bucket + (size_t)bin*BINW*CAP);
  for (int i = t; i < BINW*CAP/4; i += 1024) bdst[i] = bsrc[i];
  if (t < BINW) cnt[bin*BINW + t] = lc[t];
}

// K34 (fused k3+k4, conservative form): one block per 256 nodes.
// Phase 1: EXACT R9-k3 loop (1 thread/dst, sequential 4-batched gathers) —
//   numerics bit-identical to the R9 pipeline — writing normalized af[24]
//   to LDS instead of the global aggr buffer (saves 25.6MB round-trip).
// Phase 2: EXACT R9-k4 MFMA body, looped over 4 tiles of 16 nodes per wave.
__global__ __launch_bounds__(256) void k34_fused(
    const float4* __restrict__ rec, const int* __restrict__ cnt,
    const int* __restrict__ bucket, const float* __restrict__ W1,
    const float* __restrict__ b1, const unsigned short* __restrict__ Bfrag,
    const float* __restrict__ as2v, const float* __restrict__ ad2v,
    float* __restrict__ h2, float2* __restrict__ a2, int N){
  __shared__ float af_lds[256][24];   // 24KB
  int t = threadIdx.x;
  int base = blockIdx.x * 256;
  // ---- phase 1: R9-k3 verbatim ----
  {
    int n = min(base + t, N-1);
    float4 q0 = rec[n*4+0], q1 = rec[n*4+1], q2 = rec[n*4+2], q3 = rec[n*4+3];
    float xf[6] = {q0.x, q0.y, q0.z, q0.w, q1.x, q1.y};
    float as[4] = {q1.z, q1.w, q2.x, q2.y};
    float ad[4] = {q2.z, q2.w, q3.x, q3.y};
    float acc[4][6], den[4];
    for (int h = 0; h < 4; ++h){
      float e0 = __expf(leaky(as[h] + ad[h]));   // self-loop
      den[h] = e0;
      for (int f = 0; f < 6; ++f) acc[h][f] = e0 * xf[f];
    }
    int deg = min(cnt[n], CAP);
    const int* bk = bucket + (size_t)n*CAP;
    int i = 0;
    for (; i + 4 <= deg; i += 4){
      int sid[4];
      #pragma unroll
      for (int j = 0; j < 4; ++j) sid[j] = bk[i+j];
      float4 ra[4], rb[4], rc[4];
      #pragma unroll
      for (int j = 0; j < 4; ++j){
        ra[j] = rec[sid[j]*4+0]; rb[j] = rec[sid[j]*4+1]; rc[j] = rec[sid[j]*4+2];
      }
      #pragma unroll
      for (int j = 0; j < 4; ++j){
        float sx[6] = {ra[j].x, ra[j].y, ra[j].z, ra[j].w, rb[j].x, rb[j].y};
        float sa[4] = {rb[j].z, rb[j].w, rc[j].x, rc[j].y};
        #pragma unroll
        for (int h = 0; h < 4; ++h){
          float e = __expf(leaky(sa[h] + ad[h]));
          den[h] += e;
          #pragma unroll
          for (int f = 0; f < 6; ++f) acc[h][f] += e * sx[f];
        }
      }
    }
    for (; i < deg; ++i){
      int s = bk[i];
      float4 a0 = rec[s*4+0], a1 = rec[s*4+1], a2r = rec[s*4+2];
      float sx[6] = {a0.x, a0.y, a0.z, a0.w, a1.x, a1.y};
      float sa[4] = {a1.z, a1.w, a2r.x, a2r.y};
      for (int h = 0; h < 4; ++h){
        float e = __expf(leaky(sa[h] + ad[h]));
        den[h] += e;
        for (int f = 0; f < 6; ++f) acc[h][f] += e * sx[f];
      }
    }
    #pragma unroll
    for (int h = 0; h < 4; ++h){
      float dinv = 1.f / den[h];
      #pragma unroll
      for (int f = 0; f < 6; ++f) af_lds[t][h*6 + f] = acc[h][f] * dinv;
    }
  }
  __syncthreads();

  // ---- phase 2: R9-k4 body, 4 tiles of 16 nodes per wave ----
  int L = t & 63, w = t >> 6;
  int m = L & 15, quad = L >> 4;
  float asv[4], adv[4];
  #pragma unroll
  for (int ct = 0; ct < 4; ++ct){ asv[ct] = as2v[ct*16 + m]; adv[ct] = ad2v[ct*16 + m]; }

  for (int g = 0; g < 4; ++g){
    int row = w*64 + g*16 + m;           // block-local node supplying A-frag
    float af[24];
    {
      const float4* afl = (const float4*)&af_lds[row][0];  // 96B stride, 16B aligned
      #pragma unroll
      for (int i = 0; i < 6; ++i){
        float4 v = afl[i];
        af[i*4+0] = v.x; af[i*4+1] = v.y; af[i*4+2] = v.z; af[i*4+3] = v.w;
      }
    }
    f32x4 acc4[4];
    #pragma unroll
    for (int ct = 0; ct < 4; ++ct) acc4[ct] = (f32x4){0.f, 0.f, 0.f, 0.f};

    #pragma unroll
    for (int ks = 0; ks < 8; ++ks){
      int kb = ks*32 + quad*8;           // 8-aligned, stays within one head chunk
      int kc = kb >> 6;
      const float* afk = af + kc*6;
      float4 bb0 = *(const float4*)(b1 + kb);
      float4 bb1 = *(const float4*)(b1 + kb + 4);
      float s0=bb0.x, s1=bb0.y, s2=bb0.z, s3=bb0.w;
      float s4=bb1.x, s5=bb1.y, s6=bb1.z, s7=bb1.w;
      #pragma unroll
      for (int f = 0; f < 6; ++f){
        float a = afk[f];
        float4 w0 = *(const float4*)(W1 + f*256 + kb);
        float4 w1 = *(const float4*)(W1 + f*256 + kb + 4);
        s0 += a*w0.x; s1 += a*w0.y; s2 += a*w0.z; s3 += a*w0.w;
        s4 += a*w1.x; s5 += a*w1.y; s6 += a*w1.z; s7 += a*w1.w;
      }
      ushort8 ap;
      ap[0]=f2bf(eluf(s0)); ap[1]=f2bf(eluf(s1)); ap[2]=f2bf(eluf(s2)); ap[3]=f2bf(eluf(s3));
      ap[4]=f2bf(eluf(s4)); ap[5]=f2bf(eluf(s5)); ap[6]=f2bf(eluf(s6)); ap[7]=f2bf(eluf(s7));
      bf16x8 av = __builtin_bit_cast(bf16x8, ap);
      #pragma unroll
      for (int ct = 0; ct < 4; ++ct){
        bf16x8 bv = *(const bf16x8*)(Bfrag + (size_t)(((ks*4 + ct)*64 + L) * 8));
        acc4[ct] = __builtin_amdgcn_mfma_f32_16x16x32_bf16(av, bv, acc4[ct], 0, 0, 0);
      }
    }

    // epilogue for this 16-node tile
    float ps[4] = {0,0,0,0}, pd[4] = {0,0,0,0};
    #pragma unroll
    for (int ct = 0; ct < 4; ++ct)
      #pragma unroll
      for (int r = 0; r < 4; ++r){
        ps[r] += acc4[ct][r] * asv[ct];
        pd[r] += acc4[ct][r] * adv[ct];
      }
    #pragma unroll
    for (int r = 0; r < 4; ++r){
      int nr = base + w*64 + g*16 + quad*4 + r;
      if (nr < N){
        #pragma unroll
        for (int ct = 0; ct < 4; ++ct)
          h2[(size_t)nr*64 + ct*16 + m] = acc4[ct][r];
      }
    }
    #pragma unroll
    for (int mask = 1; mask <= 8; mask <<= 1){
      #pragma unroll
      for (int r = 0; r < 4; ++r){
        ps[r] += __shfl_xor(ps[r], mask, 64);
        pd[r] += __shfl_xor(pd[r], mask, 64);
      }
    }
    if (m == 0){
      #pragma unroll
      for (int r = 0; r < 4; ++r){
        int nr = base + w*64 + g*16 + quad*4 + r;
        if (nr < N) a2[nr] = make_float2(ps[r], pd[r]);
      }
    }
  }
}

// K5: layer-2 aggregation only for drone dsts (first ND) + elu + MLP head.
__global__ __launch_bounds__(256) void k5_out(
    const float* __restrict__ h2, const float2* __restrict__ a2,
    const int* __restrict__ cnt, const int* __restrict__ bucket,
    const float* __restrict__ b2, const float* __restrict__ fc1w,
    const float* __restrict__ fc1b, const float* __restrict__ fc2w,
    const float* __restrict__ fc2b, float* __restrict__ out, int ND){
  __shared__ float hb[4][64];
  int lane = threadIdx.x & 63;
  int w = threadIdx.x >> 6;
  int n = blockIdx.x * 4 + w;
  if (n >= ND) return;
  float2 self = a2[n];
  float adv = self.y;
  float e0 = __expf(leaky(self.x + adv));
  float den = e0;
  float acc = e0 * h2[n*64 + lane];
  int deg = min(cnt[n], CAP);
  const int* bk = bucket + (size_t)n*CAP;
  int i = 0;
  for (; i + 4 <= deg; i += 4){
    int sid[4];
    #pragma unroll
    for (int j = 0; j < 4; ++j) sid[j] = bk[i+j];
    float av[4], hv4[4];
    #pragma unroll
    for (int j = 0; j < 4; ++j){
      av[j] = a2[sid[j]].x;
      hv4[j] = h2[(size_t)sid[j]*64 + lane];
    }
    #pragma unroll
    for (int j = 0; j < 4; ++j){
      float e = __expf(leaky(av[j] + adv));
      den += e;
      acc += e * hv4[j];
    }
  }
  for (; i < deg; ++i){
    int s = bk[i];
    float e = __expf(leaky(a2[s].x + adv));
    den += e;
    acc += e * h2[(size_t)s*64 + lane];
  }
  float hv = eluf(acc / den + b2[lane]);
  hb[w][lane] = hv;               // wave-local LDS (lockstep wave64)
  float t1 = fc1b[lane];
  for (int k = 0; k < 64; ++k) t1 += hb[w][k] * fc1w[k*64 + lane];
  t1 = fmaxf(t1, 0.f);
  float p0 = t1 * fc2w[lane*2 + 0];
  float p1 = t1 * fc2w[lane*2 + 1];
  for (int o = 32; o > 0; o >>= 1){
    p0 += __shfl_down(p0, o, 64);
    p1 += __shfl_down(p1, o, 64);
  }
  if (lane == 0){
    out[n*2 + 0] = tanhf(p0 + fc2b[0]) * 2.f;
    out[n*2 + 1] = tanhf(p1 + fc2b[1]) * 2.f;
  }
}

extern "C" void kernel_launch(void* const* d_in, const int* in_sizes, int n_in,
                              void* d_out, int out_size, void* d_ws, size_t ws_size,
                              hipStream_t stream){
  const float* x    = (const float*)d_in[0];
  const int*   ei   = (const int*)d_in[1];    // harness passes integers as int32
  const float* W1   = (const float*)d_in[3];
  const float* as1  = (const float*)d_in[4];
  const float* ad1  = (const float*)d_in[5];
  const float* b1   = (const float*)d_in[6];
  const float* W2   = (const float*)d_in[7];
  const float* as2  = (const float*)d_in[8];
  const float* ad2  = (const float*)d_in[9];
  const float* b2   = (const float*)d_in[10];
  const float* fc1w = (const float*)d_in[11];
  const float* fc1b = (const float*)d_in[12];
  const float* fc2w = (const float*)d_in[13];
  const float* fc2b = (const float*)d_in[14];
  float* out = (float*)d_out;

  int N  = in_sizes[0] / 6;
  int E  = in_sizes[1] / 2;
  int ND = out_size / 2;
  int NR = (N + BINW - 1) >> PARTBITS;   // number of dst bins

  char* p = (char*)d_ws;
  auto alloc = [&](size_t bytes){ void* r = (void*)p; p += (bytes + 255) & ~(size_t)255; return r; };
  int*            cnt    = (int*)           alloc((size_t)NR * BINW * 4);
  int*            bucket = (int*)           alloc((size_t)NR * BINW * CAP * 4);
  float4*         rec    = (float4*)        alloc((size_t)N * 64);
  float*          h2     = (float*)         alloc((size_t)N * 256);
  float2*         a2     = (float2*)        alloc((size_t)N * 8);
  unsigned short* Bfrag  = (unsigned short*)alloc(16384 * 2);
  i32x2*          queue  = (i32x2*)         alloc((size_t)NR * NB * SEGCAP * 8);
  int*            qcnt   = (int*)           alloc((size_t)NR * NB * 4);

  size_t needed = (size_t)(p - (char*)d_ws);
  if (needed > ws_size) return;   // clean fail instead of GPU fault

  k1_att1<<<(N + 255)/256, 256, 0, stream>>>(x, W1, as1, ad1, W2, Bfrag, rec, N);
  k2a_route<<<NB, 256, 0, stream>>>(ei, E, NR, queue, qcnt);
  k2b_build<<<NR, 1024, 0, stream>>>(queue, qcnt, cnt, bucket);
  k34_fused<<<(N + 255)/256, 256, 0, stream>>>(rec, cnt, bucket, W1, b1, Bfrag,
                                               as2, ad2, h2, a2, N);
  k5_out<<<(ND + 3)/4, 256, 0, stream>>>(h2, a2, cnt, bucket, b2,
                                         fc1w, fc1b, fc2w, fc2b, out, ND);
}

// Round 12
// 206.570 us; speedup vs baseline: 1.3065x; 1.3065x over previous
//
#include <hip/hip_runtime.h>
#include <hip/hip_fp16.h>
#include <math.h>

#define CAP 48       // max bucketed in-degree; Poisson(16), P(deg>=48) ~ 8e-11/node
#define PARTBITS 8   // 256 dsts per bin
#define BINW 256
#define NB 240       // routing blocks (phase A)
#define SEGCAP 48    // per-(bin,block) queue segment; mean 17, 7.5 sigma

typedef float f32x4 __attribute__((ext_vector_type(4)));
typedef __bf16 bf16x8 __attribute__((ext_vector_type(8)));
typedef unsigned short ushort8 __attribute__((ext_vector_type(8)));
typedef int i32x4 __attribute__((ext_vector_type(4)));
typedef int i32x2 __attribute__((ext_vector_type(2)));

__device__ __forceinline__ float leaky(float x){ return x > 0.f ? x : 0.2f * x; }
__device__ __forceinline__ float eluf(float x){ return x > 0.f ? x : __expf(x) - 1.f; }
__device__ __forceinline__ unsigned short f2bf(float f){  // RNE float->bf16
  unsigned u = __float_as_uint(f);
  u += 0x7FFF + ((u >> 16) & 1);
  return (unsigned short)(u >> 16);
}
__device__ __forceinline__ float bf2f(unsigned short u){
  return __uint_as_float(((unsigned)u) << 16);
}
__device__ __forceinline__ unsigned short f2h(float f){
  return __half_as_ushort(__float2half(f));
}
__device__ __forceinline__ float h2f(unsigned short u){
  return __half2float(__ushort_as_half(u));
}

// K1: compute vw in LDS, emit COMPACT 32B node record (R11 lesson: gather cost
// ~ payload bytes; 3.2MB rec fits one XCD L2):
//   v0 = {x0..x5 bf16, as0,as1 fp16}; v1 = {as2,as3, ad0..ad3 fp16, 0,0}
// Also (first 64 blocks) pre-pack W2 into bf16 MFMA B-fragment lane order.
__global__ __launch_bounds__(256) void k1_att1(const float* __restrict__ x,
    const float* __restrict__ W1, const float* __restrict__ as1,
    const float* __restrict__ ad1, const float* __restrict__ W2,
    unsigned short* __restrict__ Bfrag, ushort8* __restrict__ rec8, int N){
  __shared__ float vw[48];
  int t = threadIdx.x;
  int gid = blockIdx.x * 256 + t;
  if (gid < 16384){
    int j  = gid & 7;
    int L  = (gid >> 3) & 63;
    int ct = (gid >> 9) & 3;
    int ks = gid >> 11;
    int k = ks*32 + ((L >> 4) & 3)*8 + j;
    int c = ct*16 + (L & 15);
    Bfrag[gid] = f2bf(W2[k*64 + c]);
  }
  if (t < 48){
    int side = t / 24, r = t % 24, f = r / 4, h = r % 4;
    const float* att = side ? ad1 : as1;
    float s = 0.f;
    for (int c = 0; c < 64; ++c) s += W1[f*256 + h*64 + c] * att[h*64 + c];
    vw[side*24 + f*4 + h] = s;
  }
  __syncthreads();
  int n = gid;
  if (n >= N) return;
  float xf[6];
  for (int f = 0; f < 6; ++f) xf[f] = x[n*6 + f];
  float as[4], ad[4];
  for (int h = 0; h < 4; ++h){
    float s = 0.f, d = 0.f;
    for (int f = 0; f < 6; ++f){ s += xf[f] * vw[f*4 + h]; d += xf[f] * vw[24 + f*4 + h]; }
    as[h] = s; ad[h] = d;
  }
  ushort8 v0, v1;
  v0[0]=f2bf(xf[0]); v0[1]=f2bf(xf[1]); v0[2]=f2bf(xf[2]); v0[3]=f2bf(xf[3]);
  v0[4]=f2bf(xf[4]); v0[5]=f2bf(xf[5]); v0[6]=f2h(as[0]); v0[7]=f2h(as[1]);
  v1[0]=f2h(as[2]); v1[1]=f2h(as[3]); v1[2]=f2h(ad[0]); v1[3]=f2h(ad[1]);
  v1[4]=f2h(ad[2]); v1[5]=f2h(ad[3]); v1[6]=0; v1[7]=0;
  rec8[n*2 + 0] = v0;
  rec8[n*2 + 1] = v1;
}

// K2a: route edges into per-(bin,block) queue segments; ranks from block-local
// LDS counters — zero global atomics. EXACT R9 version (replay-check proven).
__global__ __launch_bounds__(256) void k2a_route(const int* __restrict__ ei,
    int E, int NR, i32x2* __restrict__ queue, int* __restrict__ qcnt){
  __shared__ int lcnt[512];
  int t = threadIdx.x, blk = blockIdx.x;
  for (int i = t; i < NR; i += 256) lcnt[i] = 0;
  __syncthreads();
  int E4 = E >> 2;
  const i32x4* s4 = (const i32x4*)ei;
  const i32x4* d4 = (const i32x4*)(ei + E);
  for (int i = blk*256 + t; i < E4; i += NB*256){
    i32x4 s = __builtin_nontemporal_load(s4 + i);
    i32x4 d = __builtin_nontemporal_load(d4 + i);
    #pragma unroll
    for (int j = 0; j < 4; ++j){
      int p = d[j] >> PARTBITS;
      int r = atomicAdd(&lcnt[p], 1);
      if (r < SEGCAP){ i32x2 v = {d[j], s[j]}; queue[((size_t)p*NB + blk)*SEGCAP + r] = v; }
    }
  }
  if (blk == 0 && t < (E & 3)){
    int e = E4*4 + t;
    int dd = ei[E + e], ss = ei[e];
    int p = dd >> PARTBITS;
    int r = atomicAdd(&lcnt[p], 1);
    if (r < SEGCAP){ i32x2 v = {dd, ss}; queue[((size_t)p*NB + blk)*SEGCAP + r] = v; }
  }
  __syncthreads();
  for (int i = t; i < NR; i += 256) qcnt[(size_t)i*NB + blk] = lcnt[i];
}

// K2b: one block per bin (256 dsts). Coalesced segment reads -> LDS scatter
// (49KB slab, LDS atomics) -> dense int4 write-out. EXACT R9 version.
__global__ __launch_bounds__(1024) void k2b_build(const i32x2* __restrict__ queue,
    const int* __restrict__ qcnt, int* __restrict__ cnt, int* __restrict__ bucket){
  __shared__ int lc[BINW];
  __shared__ int lq[NB];
  __shared__ int lbuck[BINW*CAP];   // 49KB
  int t = threadIdx.x, bin = blockIdx.x;
  if (t < BINW) lc[t] = 0;
  for (int i = t; i < NB; i += 1024) lq[i] = min(qcnt[(size_t)bin*NB + i], SEGCAP);
  __syncthreads();
  const i32x2* q = queue + (size_t)bin*NB*SEGCAP;
  const int T = NB * SEGCAP;
  for (int idx = t; idx < T; idx += 1024){
    int b = idx / SEGCAP;
    int i = idx - b*SEGCAP;
    if (i < lq[b]){
      i32x2 pr = q[idx];
      int ld = pr.x & (BINW-1);
      int pos = atomicAdd(&lc[ld], 1);
      if (pos < CAP) lbuck[ld*CAP + pos] = pr.y;
    }
  }
  __syncthreads();
  const int4* bsrc = (const int4*)lbuck;
  int4* bdst = (int4*)(bucket + (size_t)bin*BINW*CAP);
  for (int i = t; i < BINW*CAP/4; i += 1024) bdst[i] = bsrc[i];
  if (t < BINW) cnt[bin*BINW + t] = lc[t];
}

// K3: per-NODE layer-1 softmax-aggregate, all 4 heads (R9 structure, compact
// 32B record gathers: 2 x ushort8 per source, 8 loads in flight per batch).
// Output packed 128B/node: aggr[n*32 + h*6 + f] = acc, aggr[n*32 + 24 + h] = den.
__global__ __launch_bounds__(256) void k3_agg1(const ushort8* __restrict__ rec8,
    const int* __restrict__ cnt, const int* __restrict__ bucket,
    float* __restrict__ aggr, int N){
  int n = blockIdx.x * 256 + threadIdx.x;
  if (n >= N) return;
  ushort8 v0 = rec8[n*2+0], v1 = rec8[n*2+1];
  float xf[6] = {bf2f(v0[0]), bf2f(v0[1]), bf2f(v0[2]), bf2f(v0[3]), bf2f(v0[4]), bf2f(v0[5])};
  float as[4] = {h2f(v0[6]), h2f(v0[7]), h2f(v1[0]), h2f(v1[1])};
  float ad[4] = {h2f(v1[2]), h2f(v1[3]), h2f(v1[4]), h2f(v1[5])};
  float acc[4][6], den[4];
  for (int h = 0; h < 4; ++h){
    float e0 = __expf(leaky(as[h] + ad[h]));   // self-loop
    den[h] = e0;
    for (int f = 0; f < 6; ++f) acc[h][f] = e0 * xf[f];
  }
  int deg = min(cnt[n], CAP);
  const int* bk = bucket + (size_t)n*CAP;
  int i = 0;
  for (; i + 4 <= deg; i += 4){
    int sid[4];
    #pragma unroll
    for (int j = 0; j < 4; ++j) sid[j] = bk[i+j];
    ushort8 ra[4], rb[4];
    #pragma unroll
    for (int j = 0; j < 4; ++j){
      ra[j] = rec8[sid[j]*2+0]; rb[j] = rec8[sid[j]*2+1];
    }
    #pragma unroll
    for (int j = 0; j < 4; ++j){
      float sx[6] = {bf2f(ra[j][0]), bf2f(ra[j][1]), bf2f(ra[j][2]),
                     bf2f(ra[j][3]), bf2f(ra[j][4]), bf2f(ra[j][5])};
      float sa[4] = {h2f(ra[j][6]), h2f(ra[j][7]), h2f(rb[j][0]), h2f(rb[j][1])};
      #pragma unroll
      for (int h = 0; h < 4; ++h){
        float e = __expf(leaky(sa[h] + ad[h]));
        den[h] += e;
        #pragma unroll
        for (int f = 0; f < 6; ++f) acc[h][f] += e * sx[f];
      }
    }
  }
  for (; i < deg; ++i){
    int s = bk[i];
    ushort8 a0 = rec8[s*2+0], a1 = rec8[s*2+1];
    float sx[6] = {bf2f(a0[0]), bf2f(a0[1]), bf2f(a0[2]), bf2f(a0[3]), bf2f(a0[4]), bf2f(a0[5])};
    float sa[4] = {h2f(a0[6]), h2f(a0[7]), h2f(a1[0]), h2f(a1[1])};
    for (int h = 0; h < 4; ++h){
      float e = __expf(leaky(sa[h] + ad[h]));
      den[h] += e;
      for (int f = 0; f < 6; ++f) acc[h][f] += e * sx[f];
    }
  }
  float4* o = (float4*)(aggr + (size_t)n*32);
  o[0] = make_float4(acc[0][0], acc[0][1], acc[0][2], acc[0][3]);
  o[1] = make_float4(acc[0][4], acc[0][5], acc[1][0], acc[1][1]);
  o[2] = make_float4(acc[1][2], acc[1][3], acc[1][4], acc[1][5]);
  o[3] = make_float4(acc[2][0], acc[2][1], acc[2][2], acc[2][3]);
  o[4] = make_float4(acc[2][4], acc[2][5], acc[3][0], acc[3][1]);
  o[5] = make_float4(acc[3][2], acc[3][3], acc[3][4], acc[3][5]);
  o[6] = make_float4(den[0], den[1], den[2], den[3]);
}

// K4 (MFMA): per-wave 16 nodes, R9-proven body. h2 now stored fp16 (halves
// k5's gather volume). C/D: col=lane&15, row=(lane>>4)*4+reg. [m89]
__global__ __launch_bounds__(256) void k4_mfma(
    const float* __restrict__ aggr, const float* __restrict__ W1,
    const float* __restrict__ b1, const unsigned short* __restrict__ Bfrag,
    const float* __restrict__ as2v, const float* __restrict__ ad2v,
    unsigned short* __restrict__ h2h, float2* __restrict__ a2, int N){
  int t = threadIdx.x;
  int L = t & 63;
  int w = t >> 6;
  int base = blockIdx.x * 64;
  int m = L & 15;
  int quad = L >> 4;
  int na = base + w*16 + m;
  int nc = min(na, N-1);
  const float4* A4 = (const float4*)(aggr + (size_t)nc*32);
  float4 q0=A4[0], q1=A4[1], q2=A4[2], q3=A4[3], q4=A4[4], q5=A4[5], q6=A4[6];
  float d0=1.f/q6.x, d1=1.f/q6.y, d2=1.f/q6.z, d3=1.f/q6.w;
  float af[24];
  af[0]=q0.x*d0;  af[1]=q0.y*d0;  af[2]=q0.z*d0;  af[3]=q0.w*d0;  af[4]=q1.x*d0;  af[5]=q1.y*d0;
  af[6]=q1.z*d1;  af[7]=q1.w*d1;  af[8]=q2.x*d1;  af[9]=q2.y*d1;  af[10]=q2.z*d1; af[11]=q2.w*d1;
  af[12]=q3.x*d2; af[13]=q3.y*d2; af[14]=q3.z*d2; af[15]=q3.w*d2; af[16]=q4.x*d2; af[17]=q4.y*d2;
  af[18]=q4.z*d3; af[19]=q4.w*d3; af[20]=q5.x*d3; af[21]=q5.y*d3; af[22]=q5.z*d3; af[23]=q5.w*d3;

  f32x4 acc[4];
  #pragma unroll
  for (int ct = 0; ct < 4; ++ct) acc[ct] = (f32x4){0.f, 0.f, 0.f, 0.f};

  #pragma unroll
  for (int ks = 0; ks < 8; ++ks){
    int kb = ks*32 + quad*8;
    int kc = kb >> 6;
    const float* afk = af + kc*6;
    float4 bb0 = *(const float4*)(b1 + kb);
    float4 bb1 = *(const float4*)(b1 + kb + 4);
    float s0=bb0.x, s1=bb0.y, s2=bb0.z, s3=bb0.w;
    float s4=bb1.x, s5=bb1.y, s6=bb1.z, s7=bb1.w;
    #pragma unroll
    for (int f = 0; f < 6; ++f){
      float a = afk[f];
      float4 w0 = *(const float4*)(W1 + f*256 + kb);
      float4 w1 = *(const float4*)(W1 + f*256 + kb + 4);
      s0 += a*w0.x; s1 += a*w0.y; s2 += a*w0.z; s3 += a*w0.w;
      s4 += a*w1.x; s5 += a*w1.y; s6 += a*w1.z; s7 += a*w1.w;
    }
    ushort8 ap;
    ap[0]=f2bf(eluf(s0)); ap[1]=f2bf(eluf(s1)); ap[2]=f2bf(eluf(s2)); ap[3]=f2bf(eluf(s3));
    ap[4]=f2bf(eluf(s4)); ap[5]=f2bf(eluf(s5)); ap[6]=f2bf(eluf(s6)); ap[7]=f2bf(eluf(s7));
    bf16x8 av = __builtin_bit_cast(bf16x8, ap);
    #pragma unroll
    for (int ct = 0; ct < 4; ++ct){
      bf16x8 bv = *(const bf16x8*)(Bfrag + (size_t)(((ks*4 + ct)*64 + L) * 8));
      acc[ct] = __builtin_amdgcn_mfma_f32_16x16x32_bf16(av, bv, acc[ct], 0, 0, 0);
    }
  }

  float asv[4], adv[4];
  #pragma unroll
  for (int ct = 0; ct < 4; ++ct){ asv[ct] = as2v[ct*16 + m]; adv[ct] = ad2v[ct*16 + m]; }
  float ps[4] = {0,0,0,0}, pd[4] = {0,0,0,0};
  #pragma unroll
  for (int ct = 0; ct < 4; ++ct)
    #pragma unroll
    for (int r = 0; r < 4; ++r){
      ps[r] += acc[ct][r] * asv[ct];
      pd[r] += acc[ct][r] * adv[ct];
    }
  #pragma unroll
  for (int r = 0; r < 4; ++r){
    int nr = base + w*16 + quad*4 + r;
    if (nr < N){
      #pragma unroll
      for (int ct = 0; ct < 4; ++ct)
        h2h[(size_t)nr*64 + ct*16 + m] = f2h(acc[ct][r]);
    }
  }
  #pragma unroll
  for (int mask = 1; mask <= 8; mask <<= 1){
    #pragma unroll
    for (int r = 0; r < 4; ++r){
      ps[r] += __shfl_xor(ps[r], mask, 64);
      pd[r] += __shfl_xor(pd[r], mask, 64);
    }
  }
  if (m == 0){
    #pragma unroll
    for (int r = 0; r < 4; ++r){
      int nr = base + w*16 + quad*4 + r;
      if (nr < N) a2[nr] = make_float2(ps[r], pd[r]);
    }
  }
}

// K5: layer-2 aggregation only for drone dsts (first ND) + elu + MLP head.
// h2 gathers now fp16: 128B per source per wave (was 256B).
__global__ __launch_bounds__(256) void k5_out(
    const unsigned short* __restrict__ h2h, const float2* __restrict__ a2,
    const int* __restrict__ cnt, const int* __restrict__ bucket,
    const float* __restrict__ b2, const float* __restrict__ fc1w,
    const float* __restrict__ fc1b, const float* __restrict__ fc2w,
    const float* __restrict__ fc2b, float* __restrict__ out, int ND){
  __shared__ float hb[4][64];
  int lane = threadIdx.x & 63;
  int w = threadIdx.x >> 6;
  int n = blockIdx.x * 4 + w;
  if (n >= ND) return;
  float2 self = a2[n];
  float adv = self.y;
  float e0 = __expf(leaky(self.x + adv));
  float den = e0;
  float acc = e0 * h2f(h2h[(size_t)n*64 + lane]);
  int deg = min(cnt[n], CAP);
  const int* bk = bucket + (size_t)n*CAP;
  int i = 0;
  for (; i + 4 <= deg; i += 4){
    int sid[4];
    #pragma unroll
    for (int j = 0; j < 4; ++j) sid[j] = bk[i+j];
    float av[4]; unsigned short hv4[4];
    #pragma unroll
    for (int j = 0; j < 4; ++j){
      av[j] = a2[sid[j]].x;
      hv4[j] = h2h[(size_t)sid[j]*64 + lane];
    }
    #pragma unroll
    for (int j = 0; j < 4; ++j){
      float e = __expf(leaky(av[j] + adv));
      den += e;
      acc += e * h2f(hv4[j]);
    }
  }
  for (; i < deg; ++i){
    int s = bk[i];
    float e = __expf(leaky(a2[s].x + adv));
    den += e;
    acc += e * h2f(h2h[(size_t)s*64 + lane]);
  }
  float hv = eluf(acc / den + b2[lane]);
  hb[w][lane] = hv;               // wave-local LDS (lockstep wave64)
  float t1 = fc1b[lane];
  for (int k = 0; k < 64; ++k) t1 += hb[w][k] * fc1w[k*64 + lane];
  t1 = fmaxf(t1, 0.f);
  float p0 = t1 * fc2w[lane*2 + 0];
  float p1 = t1 * fc2w[lane*2 + 1];
  for (int o = 32; o > 0; o >>= 1){
    p0 += __shfl_down(p0, o, 64);
    p1 += __shfl_down(p1, o, 64);
  }
  if (lane == 0){
    out[n*2 + 0] = tanhf(p0 + fc2b[0]) * 2.f;
    out[n*2 + 1] = tanhf(p1 + fc2b[1]) * 2.f;
  }
}

extern "C" void kernel_launch(void* const* d_in, const int* in_sizes, int n_in,
                              void* d_out, int out_size, void* d_ws, size_t ws_size,
                              hipStream_t stream){
  const float* x    = (const float*)d_in[0];
  const int*   ei   = (const int*)d_in[1];    // harness passes integers as int32
  const float* W1   = (const float*)d_in[3];
  const float* as1  = (const float*)d_in[4];
  const float* ad1  = (const float*)d_in[5];
  const float* b1   = (const float*)d_in[6];
  const float* W2   = (const float*)d_in[7];
  const float* as2  = (const float*)d_in[8];
  const float* ad2  = (const float*)d_in[9];
  const float* b2   = (const float*)d_in[10];
  const float* fc1w = (const float*)d_in[11];
  const float* fc1b = (const float*)d_in[12];
  const float* fc2w = (const float*)d_in[13];
  const float* fc2b = (const float*)d_in[14];
  float* out = (float*)d_out;

  int N  = in_sizes[0] / 6;
  int E  = in_sizes[1] / 2;
  int ND = out_size / 2;
  int NR = (N + BINW - 1) >> PARTBITS;   // number of dst bins

  char* p = (char*)d_ws;
  auto alloc = [&](size_t bytes){ void* r = (void*)p; p += (bytes + 255) & ~(size_t)255; return r; };
  int*            cnt    = (int*)           alloc((size_t)NR * BINW * 4);
  int*            bucket = (int*)           alloc((size_t)NR * BINW * CAP * 4);
  ushort8*        rec8   = (ushort8*)       alloc((size_t)N * 32);
  float*          aggr   = (float*)         alloc((size_t)N * 128);
  unsigned short* h2h    = (unsigned short*)alloc((size_t)N * 128);
  float2*         a2     = (float2*)        alloc((size_t)N * 8);
  unsigned short* Bfrag  = (unsigned short*)alloc(16384 * 2);
  i32x2*          queue  = (i32x2*)         alloc((size_t)NR * NB * SEGCAP * 8);
  int*            qcnt   = (int*)           alloc((size_t)NR * NB * 4);

  size_t needed = (size_t)(p - (char*)d_ws);
  if (needed > ws_size) return;   // clean fail instead of GPU fault

  k1_att1<<<(N + 255)/256, 256, 0, stream>>>(x, W1, as1, ad1, W2, Bfrag, rec8, N);
  k2a_route<<<NB, 256, 0, stream>>>(ei, E, NR, queue, qcnt);
  k2b_build<<<NR, 1024, 0, stream>>>(queue, qcnt, cnt, bucket);
  k3_agg1<<<(N + 255)/256, 256, 0, stream>>>(rec8, cnt, bucket, aggr, N);
  k4_mfma<<<(N + 63)/64, 256, 0, stream>>>(aggr, W1, b1, Bfrag, as2, ad2, h2h, a2, N);
  k5_out<<<(ND + 3)/4, 256, 0, stream>>>(h2h, a2, cnt, bucket, b2,
                                         fc1w, fc1b, fc2w, fc2b, out, ND);
}

// Round 13
// 191.571 us; speedup vs baseline: 1.4088x; 1.0783x over previous
//
#include <hip/hip_runtime.h>
#include <hip/hip_fp16.h>
#include <math.h>

#define CAP 48       // max bucketed in-degree; Poisson(16), P(deg>=48) ~ 8e-11/node
#define PARTBITS 8   // 256 dsts per bin
#define BINW 256
#define NB 240       // routing blocks (phase A)
#define SEGCAP 48    // per-(bin,block) queue segment; mean 17, 7.5 sigma

typedef float f32x4 __attribute__((ext_vector_type(4)));
typedef __bf16 bf16x8 __attribute__((ext_vector_type(8)));
typedef unsigned short ushort8 __attribute__((ext_vector_type(8)));
typedef int i32x4 __attribute__((ext_vector_type(4)));
typedef int i32x2 __attribute__((ext_vector_type(2)));

__device__ __forceinline__ float leaky(float x){ return x > 0.f ? x : 0.2f * x; }
__device__ __forceinline__ float eluf(float x){ return x > 0.f ? x : __expf(x) - 1.f; }
__device__ __forceinline__ unsigned short f2bf(float f){  // RNE float->bf16
  unsigned u = __float_as_uint(f);
  u += 0x7FFF + ((u >> 16) & 1);
  return (unsigned short)(u >> 16);
}
__device__ __forceinline__ float bf2f(unsigned short u){
  return __uint_as_float(((unsigned)u) << 16);
}
__device__ __forceinline__ unsigned short f2h(float f){
  return __half_as_ushort(__float2half(f));
}
__device__ __forceinline__ float h2f(unsigned short u){
  return __half2float(__ushort_as_half(u));
}

// K1: compute vw in LDS, emit COMPACT 32B node record (R12 WIN: gather cost ~
// payload bytes; 3.2MB rec fits one XCD L2):
//   v0 = {x0..x5 bf16, as0,as1 fp16}; v1 = {as2,as3, ad0..ad3 fp16, 0,0}
// Also (first 64 blocks) pre-pack W2 into bf16 MFMA B-fragment lane order.
__global__ __launch_bounds__(256) void k1_att1(const float* __restrict__ x,
    const float* __restrict__ W1, const float* __restrict__ as1,
    const float* __restrict__ ad1, const float* __restrict__ W2,
    unsigned short* __restrict__ Bfrag, ushort8* __restrict__ rec8, int N){
  __shared__ float vw[48];
  int t = threadIdx.x;
  int gid = blockIdx.x * 256 + t;
  if (gid < 16384){
    int j  = gid & 7;
    int L  = (gid >> 3) & 63;
    int ct = (gid >> 9) & 3;
    int ks = gid >> 11;
    int k = ks*32 + ((L >> 4) & 3)*8 + j;
    int c = ct*16 + (L & 15);
    Bfrag[gid] = f2bf(W2[k*64 + c]);
  }
  if (t < 48){
    int side = t / 24, r = t % 24, f = r / 4, h = r % 4;
    const float* att = side ? ad1 : as1;
    float s = 0.f;
    for (int c = 0; c < 64; ++c) s += W1[f*256 + h*64 + c] * att[h*64 + c];
    vw[side*24 + f*4 + h] = s;
  }
  __syncthreads();
  int n = gid;
  if (n >= N) return;
  float xf[6];
  for (int f = 0; f < 6; ++f) xf[f] = x[n*6 + f];
  float as[4], ad[4];
  for (int h = 0; h < 4; ++h){
    float s = 0.f, d = 0.f;
    for (int f = 0; f < 6; ++f){ s += xf[f] * vw[f*4 + h]; d += xf[f] * vw[24 + f*4 + h]; }
    as[h] = s; ad[h] = d;
  }
  ushort8 v0, v1;
  v0[0]=f2bf(xf[0]); v0[1]=f2bf(xf[1]); v0[2]=f2bf(xf[2]); v0[3]=f2bf(xf[3]);
  v0[4]=f2bf(xf[4]); v0[5]=f2bf(xf[5]); v0[6]=f2h(as[0]); v0[7]=f2h(as[1]);
  v1[0]=f2h(as[2]); v1[1]=f2h(as[3]); v1[2]=f2h(ad[0]); v1[3]=f2h(ad[1]);
  v1[4]=f2h(ad[2]); v1[5]=f2h(ad[3]); v1[6]=0; v1[7]=0;
  rec8[n*2 + 0] = v0;
  rec8[n*2 + 1] = v1;
}

// K2a: route edges into per-(bin,block) queue segments; ranks from block-local
// LDS counters — zero global atomics. EXACT R9 version (replay-check proven).
__global__ __launch_bounds__(256) void k2a_route(const int* __restrict__ ei,
    int E, int NR, i32x2* __restrict__ queue, int* __restrict__ qcnt){
  __shared__ int lcnt[512];
  int t = threadIdx.x, blk = blockIdx.x;
  for (int i = t; i < NR; i += 256) lcnt[i] = 0;
  __syncthreads();
  int E4 = E >> 2;
  const i32x4* s4 = (const i32x4*)ei;
  const i32x4* d4 = (const i32x4*)(ei + E);
  for (int i = blk*256 + t; i < E4; i += NB*256){
    i32x4 s = __builtin_nontemporal_load(s4 + i);
    i32x4 d = __builtin_nontemporal_load(d4 + i);
    #pragma unroll
    for (int j = 0; j < 4; ++j){
      int p = d[j] >> PARTBITS;
      int r = atomicAdd(&lcnt[p], 1);
      if (r < SEGCAP){ i32x2 v = {d[j], s[j]}; queue[((size_t)p*NB + blk)*SEGCAP + r] = v; }
    }
  }
  if (blk == 0 && t < (E & 3)){
    int e = E4*4 + t;
    int dd = ei[E + e], ss = ei[e];
    int p = dd >> PARTBITS;
    int r = atomicAdd(&lcnt[p], 1);
    if (r < SEGCAP){ i32x2 v = {dd, ss}; queue[((size_t)p*NB + blk)*SEGCAP + r] = v; }
  }
  __syncthreads();
  for (int i = t; i < NR; i += 256) qcnt[(size_t)i*NB + blk] = lcnt[i];
}

// K2b: one block per bin (256 dsts). Coalesced segment reads -> LDS scatter
// (49KB slab, LDS atomics) -> dense int4 write-out. EXACT R9 version.
__global__ __launch_bounds__(1024) void k2b_build(const i32x2* __restrict__ queue,
    const int* __restrict__ qcnt, int* __restrict__ cnt, int* __restrict__ bucket){
  __shared__ int lc[BINW];
  __shared__ int lq[NB];
  __shared__ int lbuck[BINW*CAP];   // 49KB
  int t = threadIdx.x, bin = blockIdx.x;
  if (t < BINW) lc[t] = 0;
  for (int i = t; i < NB; i += 1024) lq[i] = min(qcnt[(size_t)bin*NB + i], SEGCAP);
  __syncthreads();
  const i32x2* q = queue + (size_t)bin*NB*SEGCAP;
  const int T = NB * SEGCAP;
  for (int idx = t; idx < T; idx += 1024){
    int b = idx / SEGCAP;
    int i = idx - b*SEGCAP;
    if (i < lq[b]){
      i32x2 pr = q[idx];
      int ld = pr.x & (BINW-1);
      int pos = atomicAdd(&lc[ld], 1);
      if (pos < CAP) lbuck[ld*CAP + pos] = pr.y;
    }
  }
  __syncthreads();
  const int4* bsrc = (const int4*)lbuck;
  int4* bdst = (int4*)(bucket + (size_t)bin*BINW*CAP);
  for (int i = t; i < BINW*CAP/4; i += 1024) bdst[i] = bsrc[i];
  if (t < BINW) cnt[bin*BINW + t] = lc[t];
}

// K3: per-NODE layer-1 softmax-aggregate, all 4 heads, compact 32B gathers.
// EXACT R12 version.
__global__ __launch_bounds__(256) void k3_agg1(const ushort8* __restrict__ rec8,
    const int* __restrict__ cnt, const int* __restrict__ bucket,
    float* __restrict__ aggr, int N){
  int n = blockIdx.x * 256 + threadIdx.x;
  if (n >= N) return;
  ushort8 v0 = rec8[n*2+0], v1 = rec8[n*2+1];
  float xf[6] = {bf2f(v0[0]), bf2f(v0[1]), bf2f(v0[2]), bf2f(v0[3]), bf2f(v0[4]), bf2f(v0[5])};
  float as[4] = {h2f(v0[6]), h2f(v0[7]), h2f(v1[0]), h2f(v1[1])};
  float ad[4] = {h2f(v1[2]), h2f(v1[3]), h2f(v1[4]), h2f(v1[5])};
  float acc[4][6], den[4];
  for (int h = 0; h < 4; ++h){
    float e0 = __expf(leaky(as[h] + ad[h]));   // self-loop
    den[h] = e0;
    for (int f = 0; f < 6; ++f) acc[h][f] = e0 * xf[f];
  }
  int deg = min(cnt[n], CAP);
  const int* bk = bucket + (size_t)n*CAP;
  int i = 0;
  for (; i + 4 <= deg; i += 4){
    int sid[4];
    #pragma unroll
    for (int j = 0; j < 4; ++j) sid[j] = bk[i+j];
    ushort8 ra[4], rb[4];
    #pragma unroll
    for (int j = 0; j < 4; ++j){
      ra[j] = rec8[sid[j]*2+0]; rb[j] = rec8[sid[j]*2+1];
    }
    #pragma unroll
    for (int j = 0; j < 4; ++j){
      float sx[6] = {bf2f(ra[j][0]), bf2f(ra[j][1]), bf2f(ra[j][2]),
                     bf2f(ra[j][3]), bf2f(ra[j][4]), bf2f(ra[j][5])};
      float sa[4] = {h2f(ra[j][6]), h2f(ra[j][7]), h2f(rb[j][0]), h2f(rb[j][1])};
      #pragma unroll
      for (int h = 0; h < 4; ++h){
        float e = __expf(leaky(sa[h] + ad[h]));
        den[h] += e;
        #pragma unroll
        for (int f = 0; f < 6; ++f) acc[h][f] += e * sx[f];
      }
    }
  }
  for (; i < deg; ++i){
    int s = bk[i];
    ushort8 a0 = rec8[s*2+0], a1 = rec8[s*2+1];
    float sx[6] = {bf2f(a0[0]), bf2f(a0[1]), bf2f(a0[2]), bf2f(a0[3]), bf2f(a0[4]), bf2f(a0[5])};
    float sa[4] = {h2f(a0[6]), h2f(a0[7]), h2f(a1[0]), h2f(a1[1])};
    for (int h = 0; h < 4; ++h){
      float e = __expf(leaky(sa[h] + ad[h]));
      den[h] += e;
      for (int f = 0; f < 6; ++f) acc[h][f] += e * sx[f];
    }
  }
  float4* o = (float4*)(aggr + (size_t)n*32);
  o[0] = make_float4(acc[0][0], acc[0][1], acc[0][2], acc[0][3]);
  o[1] = make_float4(acc[0][4], acc[0][5], acc[1][0], acc[1][1]);
  o[2] = make_float4(acc[1][2], acc[1][3], acc[1][4], acc[1][5]);
  o[3] = make_float4(acc[2][0], acc[2][1], acc[2][2], acc[2][3]);
  o[4] = make_float4(acc[2][4], acc[2][5], acc[3][0], acc[3][1]);
  o[5] = make_float4(acc[3][2], acc[3][3], acc[3][4], acc[3][5]);
  o[6] = make_float4(den[0], den[1], den[2], den[3]);
}

// K4 (MFMA + LDS staging): R12 counters showed 42µs at VALU 20% / MFMA 2.7% /
// occupancy 28% — latency-bound on ~150 global loads/thread re-reading
// W1/b1/Bfrag from L1/L2. Stage all three in LDS once per block (39KB →
// 4 blocks/CU): hot loop global loads drop to ~10/thread. W1/b1 LDS reads are
// quad-uniform (broadcast; quads hit disjoint bank groups). Math unchanged.
__global__ __launch_bounds__(256) void k4_mfma(
    const float* __restrict__ aggr, const float* __restrict__ W1,
    const float* __restrict__ b1, const unsigned short* __restrict__ Bfrag,
    const float* __restrict__ as2v, const float* __restrict__ ad2v,
    unsigned short* __restrict__ h2h, float2* __restrict__ a2, int N){
  __shared__ float w1s[6*256];     // 6KB
  __shared__ float b1s[256];       // 1KB
  __shared__ ushort8 bfs[2048];    // 32KB
  int t = threadIdx.x;
  {
    const float4* w1g = (const float4*)W1;
    float4* w1l = (float4*)w1s;
    for (int i = t; i < 384; i += 256) w1l[i] = w1g[i];
    if (t < 64) ((float4*)b1s)[t] = ((const float4*)b1)[t];
    const ushort8* bfg = (const ushort8*)Bfrag;
    #pragma unroll
    for (int i = 0; i < 8; ++i) bfs[t + 256*i] = bfg[t + 256*i];
  }
  int L = t & 63;
  int w = t >> 6;
  int base = blockIdx.x * 64;
  int m = L & 15;
  int quad = L >> 4;
  int na = base + w*16 + m;
  int nc = min(na, N-1);
  const float4* A4 = (const float4*)(aggr + (size_t)nc*32);
  float4 q0=A4[0], q1=A4[1], q2=A4[2], q3=A4[3], q4=A4[4], q5=A4[5], q6=A4[6];
  float d0=1.f/q6.x, d1=1.f/q6.y, d2=1.f/q6.z, d3=1.f/q6.w;
  float af[24];
  af[0]=q0.x*d0;  af[1]=q0.y*d0;  af[2]=q0.z*d0;  af[3]=q0.w*d0;  af[4]=q1.x*d0;  af[5]=q1.y*d0;
  af[6]=q1.z*d1;  af[7]=q1.w*d1;  af[8]=q2.x*d1;  af[9]=q2.y*d1;  af[10]=q2.z*d1; af[11]=q2.w*d1;
  af[12]=q3.x*d2; af[13]=q3.y*d2; af[14]=q3.z*d2; af[15]=q3.w*d2; af[16]=q4.x*d2; af[17]=q4.y*d2;
  af[18]=q4.z*d3; af[19]=q4.w*d3; af[20]=q5.x*d3; af[21]=q5.y*d3; af[22]=q5.z*d3; af[23]=q5.w*d3;

  f32x4 acc[4];
  #pragma unroll
  for (int ct = 0; ct < 4; ++ct) acc[ct] = (f32x4){0.f, 0.f, 0.f, 0.f};
  __syncthreads();

  #pragma unroll
  for (int ks = 0; ks < 8; ++ks){
    int kb = ks*32 + quad*8;
    int kc = kb >> 6;
    const float* afk = af + kc*6;
    float4 bb0 = *(const float4*)(b1s + kb);
    float4 bb1 = *(const float4*)(b1s + kb + 4);
    float s0=bb0.x, s1=bb0.y, s2=bb0.z, s3=bb0.w;
    float s4=bb1.x, s5=bb1.y, s6=bb1.z, s7=bb1.w;
    #pragma unroll
    for (int f = 0; f < 6; ++f){
      float a = afk[f];
      float4 w0 = *(const float4*)(w1s + f*256 + kb);
      float4 w1 = *(const float4*)(w1s + f*256 + kb + 4);
      s0 += a*w0.x; s1 += a*w0.y; s2 += a*w0.z; s3 += a*w0.w;
      s4 += a*w1.x; s5 += a*w1.y; s6 += a*w1.z; s7 += a*w1.w;
    }
    ushort8 ap;
    ap[0]=f2bf(eluf(s0)); ap[1]=f2bf(eluf(s1)); ap[2]=f2bf(eluf(s2)); ap[3]=f2bf(eluf(s3));
    ap[4]=f2bf(eluf(s4)); ap[5]=f2bf(eluf(s5)); ap[6]=f2bf(eluf(s6)); ap[7]=f2bf(eluf(s7));
    bf16x8 av = __builtin_bit_cast(bf16x8, ap);
    #pragma unroll
    for (int ct = 0; ct < 4; ++ct){
      bf16x8 bv = __builtin_bit_cast(bf16x8, bfs[(ks*4 + ct)*64 + L]);
      acc[ct] = __builtin_amdgcn_mfma_f32_16x16x32_bf16(av, bv, acc[ct], 0, 0, 0);
    }
  }

  float asv[4], adv[4];
  #pragma unroll
  for (int ct = 0; ct < 4; ++ct){ asv[ct] = as2v[ct*16 + m]; adv[ct] = ad2v[ct*16 + m]; }
  float ps[4] = {0,0,0,0}, pd[4] = {0,0,0,0};
  #pragma unroll
  for (int ct = 0; ct < 4; ++ct)
    #pragma unroll
    for (int r = 0; r < 4; ++r){
      ps[r] += acc[ct][r] * asv[ct];
      pd[r] += acc[ct][r] * adv[ct];
    }
  #pragma unroll
  for (int r = 0; r < 4; ++r){
    int nr = base + w*16 + quad*4 + r;
    if (nr < N){
      #pragma unroll
      for (int ct = 0; ct < 4; ++ct)
        h2h[(size_t)nr*64 + ct*16 + m] = f2h(acc[ct][r]);
    }
  }
  #pragma unroll
  for (int mask = 1; mask <= 8; mask <<= 1){
    #pragma unroll
    for (int r = 0; r < 4; ++r){
      ps[r] += __shfl_xor(ps[r], mask, 64);
      pd[r] += __shfl_xor(pd[r], mask, 64);
    }
  }
  if (m == 0){
    #pragma unroll
    for (int r = 0; r < 4; ++r){
      int nr = base + w*16 + quad*4 + r;
      if (nr < N) a2[nr] = make_float2(ps[r], pd[r]);
    }
  }
}

// K5: layer-2 aggregation only for drone dsts (first ND) + elu + MLP head.
// fp16 h2 gathers. EXACT R12 version.
__global__ __launch_bounds__(256) void k5_out(
    const unsigned short* __restrict__ h2h, const float2* __restrict__ a2,
    const int* __restrict__ cnt, const int* __restrict__ bucket,
    const float* __restrict__ b2, const float* __restrict__ fc1w,
    const float* __restrict__ fc1b, const float* __restrict__ fc2w,
    const float* __restrict__ fc2b, float* __restrict__ out, int ND){
  __shared__ float hb[4][64];
  int lane = threadIdx.x & 63;
  int w = threadIdx.x >> 6;
  int n = blockIdx.x * 4 + w;
  if (n >= ND) return;
  float2 self = a2[n];
  float adv = self.y;
  float e0 = __expf(leaky(self.x + adv));
  float den = e0;
  float acc = e0 * h2f(h2h[(size_t)n*64 + lane]);
  int deg = min(cnt[n], CAP);
  const int* bk = bucket + (size_t)n*CAP;
  int i = 0;
  for (; i + 4 <= deg; i += 4){
    int sid[4];
    #pragma unroll
    for (int j = 0; j < 4; ++j) sid[j] = bk[i+j];
    float av[4]; unsigned short hv4[4];
    #pragma unroll
    for (int j = 0; j < 4; ++j){
      av[j] = a2[sid[j]].x;
      hv4[j] = h2h[(size_t)sid[j]*64 + lane];
    }
    #pragma unroll
    for (int j = 0; j < 4; ++j){
      float e = __expf(leaky(av[j] + adv));
      den += e;
      acc += e * h2f(hv4[j]);
    }
  }
  for (; i < deg; ++i){
    int s = bk[i];
    float e = __expf(leaky(a2[s].x + adv));
    den += e;
    acc += e * h2f(h2h[(size_t)s*64 + lane]);
  }
  float hv = eluf(acc / den + b2[lane]);
  hb[w][lane] = hv;               // wave-local LDS (lockstep wave64)
  float t1 = fc1b[lane];
  for (int k = 0; k < 64; ++k) t1 += hb[w][k] * fc1w[k*64 + lane];
  t1 = fmaxf(t1, 0.f);
  float p0 = t1 * fc2w[lane*2 + 0];
  float p1 = t1 * fc2w[lane*2 + 1];
  for (int o = 32; o > 0; o >>= 1){
    p0 += __shfl_down(p0, o, 64);
    p1 += __shfl_down(p1, o, 64);
  }
  if (lane == 0){
    out[n*2 + 0] = tanhf(p0 + fc2b[0]) * 2.f;
    out[n*2 + 1] = tanhf(p1 + fc2b[1]) * 2.f;
  }
}

extern "C" void kernel_launch(void* const* d_in, const int* in_sizes, int n_in,
                              void* d_out, int out_size, void* d_ws, size_t ws_size,
                              hipStream_t stream){
  const float* x    = (const float*)d_in[0];
  const int*   ei   = (const int*)d_in[1];    // harness passes integers as int32
  const float* W1   = (const float*)d_in[3];
  const float* as1  = (const float*)d_in[4];
  const float* ad1  = (const float*)d_in[5];
  const float* b1   = (const float*)d_in[6];
  const float* W2   = (const float*)d_in[7];
  const float* as2  = (const float*)d_in[8];
  const float* ad2  = (const float*)d_in[9];
  const float* b2   = (const float*)d_in[10];
  const float* fc1w = (const float*)d_in[11];
  const float* fc1b = (const float*)d_in[12];
  const float* fc2w = (const float*)d_in[13];
  const float* fc2b = (const float*)d_in[14];
  float* out = (float*)d_out;

  int N  = in_sizes[0] / 6;
  int E  = in_sizes[1] / 2;
  int ND = out_size / 2;
  int NR = (N + BINW - 1) >> PARTBITS;   // number of dst bins

  char* p = (char*)d_ws;
  auto alloc = [&](size_t bytes){ void* r = (void*)p; p += (bytes + 255) & ~(size_t)255; return r; };
  int*            cnt    = (int*)           alloc((size_t)NR * BINW * 4);
  int*            bucket = (int*)           alloc((size_t)NR * BINW * CAP * 4);
  ushort8*        rec8   = (ushort8*)       alloc((size_t)N * 32);
  float*          aggr   = (float*)         alloc((size_t)N * 128);
  unsigned short* h2h    = (unsigned short*)alloc((size_t)N * 128);
  float2*         a2     = (float2*)        alloc((size_t)N * 8);
  unsigned short* Bfrag  = (unsigned short*)alloc(16384 * 2);
  i32x2*          queue  = (i32x2*)         alloc((size_t)NR * NB * SEGCAP * 8);
  int*            qcnt   = (int*)           alloc((size_t)NR * NB * 4);

  size_t needed = (size_t)(p - (char*)d_ws);
  if (needed > ws_size) return;   // clean fail instead of GPU fault

  k1_att1<<<(N + 255)/256, 256, 0, stream>>>(x, W1, as1, ad1, W2, Bfrag, rec8, N);
  k2a_route<<<NB, 256, 0, stream>>>(ei, E, NR, queue, qcnt);
  k2b_build<<<NR, 1024, 0, stream>>>(queue, qcnt, cnt, bucket);
  k3_agg1<<<(N + 255)/256, 256, 0, stream>>>(rec8, cnt, bucket, aggr, N);
  k4_mfma<<<(N + 63)/64, 256, 0, stream>>>(aggr, W1, b1, Bfrag, as2, ad2, h2h, a2, N);
  k5_out<<<(ND + 3)/4, 256, 0, stream>>>(h2h, a2, cnt, bucket, b2,
                                         fc1w, fc1b, fc2w, fc2b, out, ND);
}